// Round 7
// baseline (269.413 us; speedup 1.0000x reference)
//
#include <hip/hip_runtime.h>
#include <cmath>

// CXLoss pipeline, revision 25: BARRIER-FREE register-streaming sweeps.
// R24 evidence: glds+counted-vmcnt left sweeps at ~41us vs 13.7us MFMA floor;
// three staging structures all ~41-48us => the 2-barrier/iter lockstep is the
// binder, not staging BW. Key insight: GT/GI are ALREADY in MFMA fragment
// order (R14 tiling) -- waves load A-fragments straight from global into a
// rotating af[16] register buffer (load for iter+1 issued right after last
// use). No LDS tile, no barriers, no waitcnt lockstep; waves fully
// independent. gC's row-max via 5-level shfl_xor (exact fmax) into 64
// per-(cs,wave) MAXP strips; gamma/beta folded per-lane into gC prologue.

#define NB 4
#define CC 256
#define HW 4096
#define NQ0 8    // p-slab loop-split (CMAX/WSUM partials)
#define NST 64   // maxv strips: 16 col-strips x 4 waves

static constexpr float kEPS = 1e-8f;
static constexpr float kSIG = 0.1f + 1e-8f;

typedef __attribute__((ext_vector_type(8)))  short short8;
typedef __attribute__((ext_vector_type(16))) float f32x16;

// workspace layout (float units)
enum {
  OFF_MEAN = 0,                        // 256 channel means
  OFF_CMAX = 256,                      // NQ0*NB*HW colmax partials
  OFF_WSUM = OFF_CMAX + NQ0*NB*HW,     // NQ0*NB*HW Wsum partials
  OFF_MAXP = OFF_WSUM + NQ0*NB*HW,     // NST*NB*HW maxv partials (4MB)
  OFF_MAXV = OFF_MAXP + NST*NB*HW,     // NB*HW maxv
  OFF_GT   = OFF_MAXV + NB*HW,         // NB*HW*CC bf16, fragment-tiled
  OFF_GI   = OFF_GT + NB*HW*CC/2,
  WS_FLOATS_FULL = OFF_GI + NB*HW*CC/2
};

__device__ __forceinline__ ushort cvt_bf16(float x) {
  unsigned u = __float_as_uint(x);
  unsigned r = (u + 0x7fffu + ((u >> 16) & 1u)) >> 16;  // round-nearest-even
  return (ushort)r;
}

__device__ __forceinline__ float blockSum256(float v) {
  __shared__ float sh[4];
  const int lane = threadIdx.x & 63, wv = threadIdx.x >> 6;
  #pragma unroll
  for (int o = 32; o > 0; o >>= 1) v += __shfl_down(v, o, 64);
  __syncthreads();
  if (lane == 0) sh[wv] = v;
  __syncthreads();
  return sh[0] + sh[1] + sh[2] + sh[3];
}

// K1: per-channel mean of featureT. grid=256
__global__ __launch_bounds__(256) void k_mean9(const float* __restrict__ fT,
                                               float* __restrict__ ws) {
  const int c = blockIdx.x, t = threadIdx.x;
  float s = 0.f;
  for (int n = 0; n < NB; ++n) {
    const float* p = fT + (size_t)(n*CC + c)*HW;
    #pragma unroll
    for (int k = 0; k < 16; ++k) s += p[k*256 + t];
  }
  const float tot = blockSum256(s);
  if (t == 0) ws[OFF_MEAN + c] = tot * (1.0f/16384.0f);
}

// K2: fused normalize + fragment-tiled bf16 write (verified R14 layout):
// offset_ushort(n, r32, kc) = ((n*128 + r32)*16 + kc)*512 + l*8
//   holds X[n][p = r32*32 + (l&31)][c = kc*16 + (l>>5)*8 + j], j<8.
// grid = 2 * NB * 128 = 1024 blocks.
__global__ __launch_bounds__(256) void k_prep9(const float* __restrict__ fT,
                                               const float* __restrict__ fI,
                                               float* __restrict__ ws) {
  __shared__ float stage[32][257];
  __shared__ float prt[8][32];
  __shared__ float sinv[32];
  const int t = threadIdx.x, l = t & 63;
  int bid = blockIdx.x;
  const int tensor = (bid >= 512); bid &= 511;
  const int n   = bid >> 7;
  const int r32 = bid & 127;
  const int p0  = r32 * 32;

  const float* __restrict__ src = tensor ? fI : fT;
  ushort* __restrict__ dst = (ushort*)(ws + (tensor ? OFF_GI : OFF_GT));
  const float* __restrict__ mean = ws + OFF_MEAN;

  const int pl = t & 31, cg = t >> 5;
  float acc = 0.f;
  #pragma unroll
  for (int i = 0; i < 32; ++i) {
    const int c = cg*32 + i;
    const float v = src[((size_t)(n*CC + c))*HW + p0 + pl] - mean[c];
    stage[pl][c] = v;
    acc += v*v;
  }
  prt[cg][pl] = acc;
  __syncthreads();
  if (t < 32) {
    float s = 0.f;
    #pragma unroll
    for (int g = 0; g < 8; ++g) s += prt[g][t];
    sinv[t] = 1.0f/(sqrtf(s) + kEPS);
  }
  __syncthreads();

  const int w = t >> 6, lhi = l >> 5, m = l & 31;
  const float iv = sinv[m];
  #pragma unroll
  for (int i = 0; i < 4; ++i) {
    const int kc = w*4 + i;
    const int cb = kc*16 + lhi*8;
    short8 o;
    #pragma unroll
    for (int j = 0; j < 8; ++j)
      ((ushort*)&o)[j] = cvt_bf16(stage[m][cb + j] * iv);
    *(short8*)(dst + (((size_t)(n*128 + r32)*16 + kc) << 9) + l*8) = o;
  }
}

// ---- shared sweep geometry (barrier-free, K_B=2) ----
// L: xcd = L&7, g = L>>3; nh = xcd*4 + (g&3); cs = g>>2.
// n = nh>>3, h = nh&7, col0 = cs*256.  (16 cs-blocks of one (n,h) share an
// XCD's L2 for the A-fragment stream.)
// wave w: B col-tiles RB0 = cs*8 + w, RB1 = cs*8 + 4 + w (q = col0+u*128+w*32+ln31).
// A-fragments read DIRECTLY from GT (fragment-tiled) into rotating af[16];
// af[kc] for iter+1 loaded right after its last use in iter.
// C/D map: col(q) = lane&31, row(p) = (r&3) + 8*(r>>2) + 4*(lane>>5).

// K3a: GEMM sweep + colmax partials. grid 512.
__global__ __launch_bounds__(256) void k_gA(
    const ushort* __restrict__ gA, const ushort* __restrict__ gB,
    float* __restrict__ ws)
{
  const int t = threadIdx.x;
  const int w = t >> 6, l = t & 63;
  const int ln31 = l & 31;

  const int L = blockIdx.x;
  const int xcd = L & 7, g = L >> 3;
  const int nh = xcd*4 + (g & 3);
  const int cs = g >> 2;
  const int n = nh >> 3, h = nh & 7;
  const int col0 = cs * 256;

  const ushort* __restrict__ gAf = gA + ((size_t)(n*128 + h*16) << 13);

  short8 breg0[16], breg1[16];
  {
    const int RB0 = cs*8 + w, RB1 = cs*8 + 4 + w;
    #pragma unroll
    for (int kc = 0; kc < 16; ++kc) {
      breg0[kc] = *(const short8*)(gB + (((size_t)(n*128 + RB0)*16 + kc) << 9) + l*8);
      breg1[kc] = *(const short8*)(gB + (((size_t)(n*128 + RB1)*16 + kc) << 9) + l*8);
    }
  }

  short8 af[16];
  #pragma unroll
  for (int kc = 0; kc < 16; ++kc)
    af[kc] = *(const short8*)(gAf + (kc << 9) + l*8);

  float run0 = -3.0e38f, run1 = -3.0e38f;

  for (int iter = 0; iter < 16; ++iter) {
    f32x16 acc0, acc1;
    #pragma unroll
    for (int e = 0; e < 16; ++e) { acc0[e] = 0.f; acc1[e] = 0.f; }
    #pragma unroll
    for (int kc = 0; kc < 16; ++kc) {
      acc0 = __builtin_amdgcn_mfma_f32_32x32x16_bf16(af[kc], breg0[kc], acc0, 0, 0, 0);
      acc1 = __builtin_amdgcn_mfma_f32_32x32x16_bf16(af[kc], breg1[kc], acc1, 0, 0, 0);
      if (iter < 15)
        af[kc] = *(const short8*)(gAf + (((iter + 1)*16 + kc) << 9) + l*8);
    }
    #pragma unroll
    for (int r = 0; r < 16; ++r) {
      run0 = fmaxf(run0, acc0[r]);
      run1 = fmaxf(run1, acc1[r]);
    }
  }

  run0 = fmaxf(run0, __shfl_xor(run0, 32, 64));
  run1 = fmaxf(run1, __shfl_xor(run1, 32, 64));
  if (l < 32) {
    float* __restrict__ C = ws + OFF_CMAX + h*(NB*HW) + n*HW + col0 + w*32 + l;
    C[0]   = run0;
    C[128] = run1;
  }
}

// K3b: GEMM sweep + Wsum partials. Per-lane a,b derived from CMAX.
__global__ __launch_bounds__(256) void k_gB(
    const ushort* __restrict__ gA, const ushort* __restrict__ gB,
    float* __restrict__ ws)
{
  const int t = threadIdx.x;
  const int w = t >> 6, l = t & 63;
  const int ln31 = l & 31;

  const int L = blockIdx.x;
  const int xcd = L & 7, g = L >> 3;
  const int nh = xcd*4 + (g & 3);
  const int cs = g >> 2;
  const int n = nh >> 3, h = nh & 7;
  const int col0 = cs * 256;

  // per-lane affine coeffs for both q columns (same op order as R24)
  float aq0, bq0, aq1, bq1;
  {
    const int q0 = col0 + w*32 + ln31;
    const int q1 = q0 + 128;
    float cm0 = -3.0e38f, cm1 = -3.0e38f;
    #pragma unroll
    for (int hh = 0; hh < NQ0; ++hh) {
      cm0 = fmaxf(cm0, ws[OFF_CMAX + hh*(NB*HW) + n*HW + q0]);
      cm1 = fmaxf(cm1, ws[OFF_CMAX + hh*(NB*HW) + n*HW + q1]);
    }
    const float i0 = 1.0f/(2.0f*(0.5f*(1.0f - cm0) + kEPS));
    const float i1 = 1.0f/(2.0f*(0.5f*(1.0f - cm1) + kEPS));
    bq0 = i0 / kSIG; aq0 = (1.0f - i0) / kSIG;
    bq1 = i1 / kSIG; aq1 = (1.0f - i1) / kSIG;
  }

  const ushort* __restrict__ gAf = gA + ((size_t)(n*128 + h*16) << 13);

  short8 breg0[16], breg1[16];
  {
    const int RB0 = cs*8 + w, RB1 = cs*8 + 4 + w;
    #pragma unroll
    for (int kc = 0; kc < 16; ++kc) {
      breg0[kc] = *(const short8*)(gB + (((size_t)(n*128 + RB0)*16 + kc) << 9) + l*8);
      breg1[kc] = *(const short8*)(gB + (((size_t)(n*128 + RB1)*16 + kc) << 9) + l*8);
    }
  }

  short8 af[16];
  #pragma unroll
  for (int kc = 0; kc < 16; ++kc)
    af[kc] = *(const short8*)(gAf + (kc << 9) + l*8);

  float ws0 = 0.f, ws1 = 0.f;

  for (int iter = 0; iter < 16; ++iter) {
    f32x16 acc0, acc1;
    #pragma unroll
    for (int e = 0; e < 16; ++e) { acc0[e] = 0.f; acc1[e] = 0.f; }
    #pragma unroll
    for (int kc = 0; kc < 16; ++kc) {
      acc0 = __builtin_amdgcn_mfma_f32_32x32x16_bf16(af[kc], breg0[kc], acc0, 0, 0, 0);
      acc1 = __builtin_amdgcn_mfma_f32_32x32x16_bf16(af[kc], breg1[kc], acc1, 0, 0, 0);
      if (iter < 15)
        af[kc] = *(const short8*)(gAf + (((iter + 1)*16 + kc) << 9) + l*8);
    }
    #pragma unroll
    for (int r = 0; r < 16; ++r) {
      ws0 += __expf(fmaf(bq0, acc0[r], aq0));
      ws1 += __expf(fmaf(bq1, acc1[r], aq1));
    }
  }

  ws0 += __shfl_xor(ws0, 32, 64);
  ws1 += __shfl_xor(ws1, 32, 64);
  if (l < 32) {
    float* __restrict__ W = ws + OFF_WSUM + h*(NB*HW) + n*HW + col0 + w*32 + l;
    W[0]   = ws0;
    W[128] = ws1;
  }
}

// K3c: GEMM sweep + row-max (maxv) partials via shfl_xor tree (exact fmax).
// gamma/beta per-lane in prologue (same formula/op-order as old k_gb9).
// MAXP strip = cs*4 + w (64 strips).
__global__ __launch_bounds__(256) void k_gC(
    const ushort* __restrict__ gA, const ushort* __restrict__ gB,
    float* __restrict__ ws)
{
  const int t = threadIdx.x;
  const int w = t >> 6, l = t & 63;
  const int ln31 = l & 31, lhi = l >> 5;

  const int L = blockIdx.x;
  const int xcd = L & 7, g = L >> 3;
  const int nh = xcd*4 + (g & 3);
  const int cs = g >> 2;
  const int n = nh >> 3, h = nh & 7;
  const int col0 = cs * 256;

  // per-lane gamma/beta for q0,q1 (formula/order == old k_gb9)
  float gq0, bq0, gq1, bq1;
  {
    const int q0 = col0 + w*32 + ln31;
    const int q1 = q0 + 128;
    float cm0 = -3.0e38f, cm1 = -3.0e38f;
    #pragma unroll
    for (int hh = 0; hh < NQ0; ++hh) {
      cm0 = fmaxf(cm0, ws[OFF_CMAX + hh*(NB*HW) + n*HW + q0]);
      cm1 = fmaxf(cm1, ws[OFF_CMAX + hh*(NB*HW) + n*HW + q1]);
    }
    float sw0 = 0.f, sw1 = 0.f;
    #pragma unroll
    for (int hh = 0; hh < NQ0; ++hh) {
      sw0 += ws[OFF_WSUM + hh*(NB*HW) + n*HW + q0];
      sw1 += ws[OFF_WSUM + hh*(NB*HW) + n*HW + q1];
    }
    const float i0 = 1.0f/(2.0f*(0.5f*(1.0f - cm0) + kEPS));
    const float i1 = 1.0f/(2.0f*(0.5f*(1.0f - cm1) + kEPS));
    bq0 = i0 / kSIG;
    bq1 = i1 / kSIG;
    gq0 = (1.0f - i0) / kSIG - logf(sw0 + kEPS);
    gq1 = (1.0f - i1) / kSIG - logf(sw1 + kEPS);
  }

  const ushort* __restrict__ gAf = gA + ((size_t)(n*128 + h*16) << 13);

  short8 breg0[16], breg1[16];
  {
    const int RB0 = cs*8 + w, RB1 = cs*8 + 4 + w;
    #pragma unroll
    for (int kc = 0; kc < 16; ++kc) {
      breg0[kc] = *(const short8*)(gB + (((size_t)(n*128 + RB0)*16 + kc) << 9) + l*8);
      breg1[kc] = *(const short8*)(gB + (((size_t)(n*128 + RB1)*16 + kc) << 9) + l*8);
    }
  }

  short8 af[16];
  #pragma unroll
  for (int kc = 0; kc < 16; ++kc)
    af[kc] = *(const short8*)(gAf + (kc << 9) + l*8);

  float* __restrict__ MAXP =
      ws + OFF_MAXP + (size_t)(cs*4 + w)*(NB*HW) + n*HW;

  for (int iter = 0; iter < 16; ++iter) {
    f32x16 acc0, acc1;
    #pragma unroll
    for (int e = 0; e < 16; ++e) { acc0[e] = 0.f; acc1[e] = 0.f; }
    #pragma unroll
    for (int kc = 0; kc < 16; ++kc) {
      acc0 = __builtin_amdgcn_mfma_f32_32x32x16_bf16(af[kc], breg0[kc], acc0, 0, 0, 0);
      acc1 = __builtin_amdgcn_mfma_f32_32x32x16_bf16(af[kc], breg1[kc], acc1, 0, 0, 0);
      if (iter < 15)
        af[kc] = *(const short8*)(gAf + (((iter + 1)*16 + kc) << 9) + l*8);
    }

    // row-max over the wave's 64 q for each of 16 p-rows; lanes 0..31 and
    // 32..63 hold different p (lhi), reduce within each 32-lane half.
    const int pb = h*512 + iter*32 + 4*lhi;
    #pragma unroll
    for (int r = 0; r < 16; ++r) {
      float v = fmaxf(fmaf(bq0, acc0[r], gq0), fmaf(bq1, acc1[r], gq1));
      v = fmaxf(v, __shfl_xor(v, 1, 64));
      v = fmaxf(v, __shfl_xor(v, 2, 64));
      v = fmaxf(v, __shfl_xor(v, 4, 64));
      v = fmaxf(v, __shfl_xor(v, 8, 64));
      v = fmaxf(v, __shfl_xor(v, 16, 64));
      if (ln31 == 0)
        MAXP[pb + (r & 3) + 8*(r >> 2)] = v;
    }
  }
}

// K6: combine 64 strip maxima. grid = 64.
__global__ __launch_bounds__(256) void k_red(float* __restrict__ ws) {
  const int idx = blockIdx.x*256 + threadIdx.x;   // n*HW + p
  float m = ws[OFF_MAXP + idx];
  #pragma unroll 8
  for (int s = 1; s < NST; ++s)
    m = fmaxf(m, ws[OFF_MAXP + s*(NB*HW) + idx]);
  ws[OFF_MAXV + idx] = m;
}

// K7: final loss. one block.
__global__ __launch_bounds__(256) void k_final9(const float* __restrict__ ws,
                                                float* __restrict__ out) {
  const int t = threadIdx.x;
  float loss = 0.f;
  for (int n = 0; n < NB; ++n) {
    float s = 0.f;
    for (int k = 0; k < 16; ++k)
      s += __expf(ws[OFF_MAXV + n*HW + k*256 + t]);
    const float tot = blockSum256(s);
    loss += -logf(tot*(1.0f/4096.0f) + kEPS);
  }
  if (t == 0) out[0] = loss*0.25f;
}

extern "C" void kernel_launch(void* const* d_in, const int* in_sizes, int n_in,
                              void* d_out, int out_size, void* d_ws, size_t ws_size,
                              hipStream_t stream) {
  const float* fT = (const float*)d_in[0];
  const float* fI = (const float*)d_in[1];
  float* out = (float*)d_out;
  float* ws  = (float*)d_ws;

  const size_t need_full = (size_t)WS_FLOATS_FULL * sizeof(float);
  if (ws_size < need_full) return;  // ~22 MB

  const ushort* GT = (const ushort*)(ws + OFF_GT);
  const ushort* GI = (const ushort*)(ws + OFF_GI);
  k_mean9 <<<256,  256, 0, stream>>>(fT, ws);
  k_prep9 <<<1024, 256, 0, stream>>>(fT, fI, ws);
  k_gA    <<<512,  256, 0, stream>>>(GT, GI, ws);   // colmax partials
  k_gB    <<<512,  256, 0, stream>>>(GT, GI, ws);   // Wsum partials
  k_gC    <<<512,  256, 0, stream>>>(GT, GI, ws);   // maxv strip partials
  k_red   <<<64,   256, 0, stream>>>(ws);           // strip combine
  k_final9<<<1,    256, 0, stream>>>(ws, out);
}

// Round 8
// 200.850 us; speedup vs baseline: 1.3414x; 1.3414x over previous
//
#include <hip/hip_runtime.h>
#include <cmath>

// CXLoss pipeline, revision 26: shared-LDS sweeps, K_A=2, ONE barrier/iter.
// R25 post-mortem: barrier-free reg-streaming collapsed (124us, 10% MfmaUtil,
// ~224 regs, latency-unhidden). R24's 41us/sweep = 840 TF = the documented
// 2-barrier m97-structure ceiling. This rev keeps R24's shared-A-in-LDS +
// glds staging and adds the two levers the ladder prescribes:
//  - K_A=2: 64-row tiles, 8 iters, 64 MFMA/wave/iter (4 acc tiles 2px2q)
//  - single __syncthreads/iter: order [sync][glds i+1 -> other buf][MFMA i]
//    [epilogue]. Barrier arrival implies prev-iter ds_reads done (lgkm waits
//    precede MFMAs), so the buffer swap is race-free with one barrier; the
//    implicit vmcnt(0) is the tile-ready wait (issued a full iter earlier).
//  - gC: no vm-ops in loop -- row-maxima stashed in LDS, MAXP stored at end.

#define NB 4
#define CC 256
#define HW 4096
#define NQ0 8    // p-slab loop-split (CMAX/WSUM partials)
#define NCS 16   // q col-strips (MAXP partials)

static constexpr float kEPS = 1e-8f;
static constexpr float kSIG = 0.1f + 1e-8f;

typedef __attribute__((ext_vector_type(8)))  short short8;
typedef __attribute__((ext_vector_type(16))) float f32x16;

// workspace layout (float units)
enum {
  OFF_MEAN = 0,                        // 256 channel means
  OFF_CMAX = 256,                      // NQ0*NB*HW colmax partials
  OFF_WSUM = OFF_CMAX + NQ0*NB*HW,     // NQ0*NB*HW Wsum partials
  OFF_MAXP = OFF_WSUM + NQ0*NB*HW,     // NCS*NB*HW maxv partials (1MB)
  OFF_MAXV = OFF_MAXP + NCS*NB*HW,     // NB*HW maxv
  OFF_GT   = OFF_MAXV + NB*HW,         // NB*HW*CC bf16, fragment-tiled
  OFF_GI   = OFF_GT + NB*HW*CC/2,
  WS_FLOATS_FULL = OFF_GI + NB*HW*CC/2
};

__device__ __forceinline__ ushort cvt_bf16(float x) {
  unsigned u = __float_as_uint(x);
  unsigned r = (u + 0x7fffu + ((u >> 16) & 1u)) >> 16;  // round-nearest-even
  return (ushort)r;
}

__device__ __forceinline__ void glds16(const ushort* g, ushort* l) {
  __builtin_amdgcn_global_load_lds(
      (const __attribute__((address_space(1))) unsigned*)g,
      (__attribute__((address_space(3))) unsigned*)l, 16, 0, 0);
}

__device__ __forceinline__ float blockSum256(float v) {
  __shared__ float sh[4];
  const int lane = threadIdx.x & 63, wv = threadIdx.x >> 6;
  #pragma unroll
  for (int o = 32; o > 0; o >>= 1) v += __shfl_down(v, o, 64);
  __syncthreads();
  if (lane == 0) sh[wv] = v;
  __syncthreads();
  return sh[0] + sh[1] + sh[2] + sh[3];
}

// K1: per-channel mean of featureT. grid=256
__global__ __launch_bounds__(256) void k_mean9(const float* __restrict__ fT,
                                               float* __restrict__ ws) {
  const int c = blockIdx.x, t = threadIdx.x;
  float s = 0.f;
  for (int n = 0; n < NB; ++n) {
    const float* p = fT + (size_t)(n*CC + c)*HW;
    #pragma unroll
    for (int k = 0; k < 16; ++k) s += p[k*256 + t];
  }
  const float tot = blockSum256(s);
  if (t == 0) ws[OFF_MEAN + c] = tot * (1.0f/16384.0f);
}

// K2: fused normalize + fragment-tiled bf16 write (verified R14 layout):
// offset_ushort(n, r32, kc) = ((n*128 + r32)*16 + kc)*512 + l*8
//   holds X[n][p = r32*32 + (l&31)][c = kc*16 + (l>>5)*8 + j], j<8.
// grid = 2 * NB * 128 = 1024 blocks.
__global__ __launch_bounds__(256) void k_prep9(const float* __restrict__ fT,
                                               const float* __restrict__ fI,
                                               float* __restrict__ ws) {
  __shared__ float stage[32][257];
  __shared__ float prt[8][32];
  __shared__ float sinv[32];
  const int t = threadIdx.x, l = t & 63;
  int bid = blockIdx.x;
  const int tensor = (bid >= 512); bid &= 511;
  const int n   = bid >> 7;
  const int r32 = bid & 127;
  const int p0  = r32 * 32;

  const float* __restrict__ src = tensor ? fI : fT;
  ushort* __restrict__ dst = (ushort*)(ws + (tensor ? OFF_GI : OFF_GT));
  const float* __restrict__ mean = ws + OFF_MEAN;

  const int pl = t & 31, cg = t >> 5;
  float acc = 0.f;
  #pragma unroll
  for (int i = 0; i < 32; ++i) {
    const int c = cg*32 + i;
    const float v = src[((size_t)(n*CC + c))*HW + p0 + pl] - mean[c];
    stage[pl][c] = v;
    acc += v*v;
  }
  prt[cg][pl] = acc;
  __syncthreads();
  if (t < 32) {
    float s = 0.f;
    #pragma unroll
    for (int g = 0; g < 8; ++g) s += prt[g][t];
    sinv[t] = 1.0f/(sqrtf(s) + kEPS);
  }
  __syncthreads();

  const int w = t >> 6, lhi = l >> 5, m = l & 31;
  const float iv = sinv[m];
  #pragma unroll
  for (int i = 0; i < 4; ++i) {
    const int kc = w*4 + i;
    const int cb = kc*16 + lhi*8;
    short8 o;
    #pragma unroll
    for (int j = 0; j < 8; ++j)
      ((ushort*)&o)[j] = cvt_bf16(stage[m][cb + j] * iv);
    *(short8*)(dst + (((size_t)(n*128 + r32)*16 + kc) << 9) + l*8) = o;
  }
}

// ---- shared sweep geometry (K_A=2, K_B=2, 1 barrier/iter) ----
// L: xcd = L&7, g = L>>3; nh = xcd*4 + (g&3); cs = g>>2.
// n = nh>>3, h = nh&7, col0 = cs*256.
// 8 iters; tile = 64 p-rows = 32KB (r32-units 2it, 2it+1), Ab[2] dbuf.
// wave w: B col-tiles RB0 = cs*8+w, RB1 = cs*8+4+w; lane q0 = col0+w*32+ln31,
// q1 = q0+128. Per iter per wave: 32 ds_read_b128 -> 64 MFMA (acc s,u).
// C/D map: col(q) = lane&31, row(p) = (r&3) + 8*(r>>2) + 4*(lane>>5).

#define SWEEP_PROLOGUE                                                        \
  const int t = threadIdx.x;                                                  \
  const int w = t >> 6, l = t & 63;                                           \
  const int ln31 = l & 31, lhi = l >> 5;  (void)lhi;                          \
  const int L = blockIdx.x;                                                   \
  const int xcd = L & 7, g = L >> 3;                                          \
  const int nh = xcd*4 + (g & 3);                                             \
  const int cs = g >> 2;                                                      \
  const int n = nh >> 3, h = nh & 7;                                          \
  const int col0 = cs * 256;

#define LOAD_BREG                                                             \
  short8 breg0[16], breg1[16];                                                \
  {                                                                           \
    const int RB0 = cs*8 + w, RB1 = cs*8 + 4 + w;                             \
    _Pragma("unroll")                                                         \
    for (int kc = 0; kc < 16; ++kc) {                                         \
      breg0[kc] = *(const short8*)(gB + (((size_t)(n*128 + RB0)*16 + kc) << 9) + l*8); \
      breg1[kc] = *(const short8*)(gB + (((size_t)(n*128 + RB1)*16 + kc) << 9) + l*8); \
    }                                                                         \
  }

#define STAGE_TILE(it_, buf_)                                                 \
  {                                                                           \
    const ushort* __restrict__ srcg = gAn + (size_t)(it_)*16384;              \
    ushort* __restrict__ dstl = &Ab[buf_][0];                                 \
    _Pragma("unroll")                                                         \
    for (int i = 0; i < 8; ++i)                                               \
      glds16(srcg + (size_t)(i*256 + t)*8, dstl + (i*256 + t)*8);             \
  }

#define MFMA_ITER(buf_)                                                       \
  f32x16 acc00, acc01, acc10, acc11;                                          \
  _Pragma("unroll")                                                           \
  for (int e = 0; e < 16; ++e) { acc00[e]=0.f; acc01[e]=0.f; acc10[e]=0.f; acc11[e]=0.f; } \
  {                                                                           \
    const ushort* __restrict__ Abuf = &Ab[buf_][0];                           \
    _Pragma("unroll")                                                         \
    for (int kc = 0; kc < 16; ++kc) {                                         \
      const short8 a0 = *(const short8*)&Abuf[kc*512 + l*8];                  \
      const short8 a1 = *(const short8*)&Abuf[8192 + kc*512 + l*8];           \
      acc00 = __builtin_amdgcn_mfma_f32_32x32x16_bf16(a0, breg0[kc], acc00, 0, 0, 0); \
      acc01 = __builtin_amdgcn_mfma_f32_32x32x16_bf16(a0, breg1[kc], acc01, 0, 0, 0); \
      acc10 = __builtin_amdgcn_mfma_f32_32x32x16_bf16(a1, breg0[kc], acc10, 0, 0, 0); \
      acc11 = __builtin_amdgcn_mfma_f32_32x32x16_bf16(a1, breg1[kc], acc11, 0, 0, 0); \
    }                                                                         \
  }

// K3a: GEMM sweep + colmax partials. grid 512, 2 blocks/CU.
__global__ __launch_bounds__(256, 2) void k_gA(
    const ushort* __restrict__ gA, const ushort* __restrict__ gB,
    float* __restrict__ ws)
{
  __shared__ ushort Ab[2][16384];   // 64KB
  __shared__ float red2[256];

  SWEEP_PROLOGUE
  const ushort* __restrict__ gAn = gA + ((size_t)(n*128 + h*16) << 13);

  STAGE_TILE(0, 0)
  LOAD_BREG

  float run0 = -3.0e38f, run1 = -3.0e38f;

  for (int it = 0; it < 8; ++it) {
    __syncthreads();                 // implicit vmcnt(0): tile it staged;
                                     // all waves past iter it-1 reads
    if (it + 1 < 8) STAGE_TILE(it + 1, (it + 1) & 1)

    MFMA_ITER(it & 1)

    #pragma unroll
    for (int r = 0; r < 16; ++r) {
      run0 = fmaxf(run0, fmaxf(acc00[r], acc10[r]));
      run1 = fmaxf(run1, fmaxf(acc01[r], acc11[r]));
    }
  }

  run0 = fmaxf(run0, __shfl_xor(run0, 32, 64));
  run1 = fmaxf(run1, __shfl_xor(run1, 32, 64));
  if (l < 32) {
    red2[w*32 + ln31]       = run0;
    red2[128 + w*32 + ln31] = run1;
  }
  __syncthreads();
  ws[OFF_CMAX + h*(NB*HW) + n*HW + col0 + t] = red2[t];
}

// K3b: GEMM sweep + Wsum partials. Per-lane a,b derived from CMAX.
__global__ __launch_bounds__(256, 2) void k_gB(
    const ushort* __restrict__ gA, const ushort* __restrict__ gB,
    float* __restrict__ ws)
{
  __shared__ ushort Ab[2][16384];
  __shared__ float red2[256];

  SWEEP_PROLOGUE
  const ushort* __restrict__ gAn = gA + ((size_t)(n*128 + h*16) << 13);

  STAGE_TILE(0, 0)

  // per-lane affine coeffs for both q columns (same op order as R24)
  float aq0, bq0, aq1, bq1;
  {
    const int q0 = col0 + w*32 + ln31;
    const int q1 = q0 + 128;
    float cm0 = -3.0e38f, cm1 = -3.0e38f;
    #pragma unroll
    for (int hh = 0; hh < NQ0; ++hh) {
      cm0 = fmaxf(cm0, ws[OFF_CMAX + hh*(NB*HW) + n*HW + q0]);
      cm1 = fmaxf(cm1, ws[OFF_CMAX + hh*(NB*HW) + n*HW + q1]);
    }
    const float i0 = 1.0f/(2.0f*(0.5f*(1.0f - cm0) + kEPS));
    const float i1 = 1.0f/(2.0f*(0.5f*(1.0f - cm1) + kEPS));
    bq0 = i0 / kSIG; aq0 = (1.0f - i0) / kSIG;
    bq1 = i1 / kSIG; aq1 = (1.0f - i1) / kSIG;
  }

  LOAD_BREG

  float ws0 = 0.f, ws1 = 0.f;

  for (int it = 0; it < 8; ++it) {
    __syncthreads();
    if (it + 1 < 8) STAGE_TILE(it + 1, (it + 1) & 1)

    MFMA_ITER(it & 1)

    #pragma unroll
    for (int r = 0; r < 16; ++r) {
      ws0 += __expf(fmaf(bq0, acc00[r], aq0));
      ws0 += __expf(fmaf(bq0, acc10[r], aq0));
      ws1 += __expf(fmaf(bq1, acc01[r], aq1));
      ws1 += __expf(fmaf(bq1, acc11[r], aq1));
    }
  }

  ws0 += __shfl_xor(ws0, 32, 64);
  ws1 += __shfl_xor(ws1, 32, 64);
  if (l < 32) {
    red2[w*32 + ln31]       = ws0;
    red2[128 + w*32 + ln31] = ws1;
  }
  __syncthreads();
  ws[OFF_WSUM + h*(NB*HW) + n*HW + col0 + t] = red2[t];
}

// K3c: GEMM sweep + row-max (maxv) partials. gamma/beta per-lane in prologue
// (same formula/op-order as before). Row-max via shfl_xor tree; per-wave
// maxima stashed in LDS (no vm-ops in loop), MAXP stored once at the end.
__global__ __launch_bounds__(256, 2) void k_gC(
    const ushort* __restrict__ gA, const ushort* __restrict__ gB,
    float* __restrict__ ws)
{
  __shared__ ushort Ab[2][16384];
  __shared__ float stash[4][512];   // 8KB: per-wave p-maxima

  SWEEP_PROLOGUE
  const ushort* __restrict__ gAn = gA + ((size_t)(n*128 + h*16) << 13);

  STAGE_TILE(0, 0)

  // per-lane gamma/beta for q0,q1 (formula/order == old k_gb9)
  float gq0, bq0, gq1, bq1;
  {
    const int q0 = col0 + w*32 + ln31;
    const int q1 = q0 + 128;
    float cm0 = -3.0e38f, cm1 = -3.0e38f;
    #pragma unroll
    for (int hh = 0; hh < NQ0; ++hh) {
      cm0 = fmaxf(cm0, ws[OFF_CMAX + hh*(NB*HW) + n*HW + q0]);
      cm1 = fmaxf(cm1, ws[OFF_CMAX + hh*(NB*HW) + n*HW + q1]);
    }
    float sw0 = 0.f, sw1 = 0.f;
    #pragma unroll
    for (int hh = 0; hh < NQ0; ++hh) {
      sw0 += ws[OFF_WSUM + hh*(NB*HW) + n*HW + q0];
      sw1 += ws[OFF_WSUM + hh*(NB*HW) + n*HW + q1];
    }
    const float i0 = 1.0f/(2.0f*(0.5f*(1.0f - cm0) + kEPS));
    const float i1 = 1.0f/(2.0f*(0.5f*(1.0f - cm1) + kEPS));
    bq0 = i0 / kSIG;
    bq1 = i1 / kSIG;
    gq0 = (1.0f - i0) / kSIG - logf(sw0 + kEPS);
    gq1 = (1.0f - i1) / kSIG - logf(sw1 + kEPS);
  }

  LOAD_BREG

  for (int it = 0; it < 8; ++it) {
    __syncthreads();
    if (it + 1 < 8) STAGE_TILE(it + 1, (it + 1) & 1)

    MFMA_ITER(it & 1)

    // row-max over the wave's 64 q per p-row; stash per wave in LDS.
    #pragma unroll
    for (int r = 0; r < 16; ++r) {
      float v0 = fmaxf(fmaf(bq0, acc00[r], gq0), fmaf(bq1, acc01[r], gq1));
      float v1 = fmaxf(fmaf(bq0, acc10[r], gq0), fmaf(bq1, acc11[r], gq1));
      #pragma unroll
      for (int o = 1; o <= 16; o <<= 1) {
        v0 = fmaxf(v0, __shfl_xor(v0, o, 64));
        v1 = fmaxf(v1, __shfl_xor(v1, o, 64));
      }
      if (ln31 == 0) {
        const int pl = it*64 + 4*lhi + (r & 3) + 8*(r >> 2);
        stash[w][pl]      = v0;
        stash[w][pl + 32] = v1;
      }
    }
  }

  __syncthreads();
  float* __restrict__ MAXP = ws + OFF_MAXP + (size_t)cs*(NB*HW) + n*HW + h*512;
  #pragma unroll
  for (int p = t; p < 512; p += 256) {
    const float m = fmaxf(fmaxf(stash[0][p], stash[1][p]),
                          fmaxf(stash[2][p], stash[3][p]));
    MAXP[p] = m;
  }
}

// K6: combine 16 col-strip maxima. grid = 64.
__global__ __launch_bounds__(256) void k_red(float* __restrict__ ws) {
  const int idx = blockIdx.x*256 + threadIdx.x;   // n*HW + p
  float m = ws[OFF_MAXP + idx];
  #pragma unroll
  for (int s = 1; s < NCS; ++s)
    m = fmaxf(m, ws[OFF_MAXP + s*(NB*HW) + idx]);
  ws[OFF_MAXV + idx] = m;
}

// K7: final loss. one block.
__global__ __launch_bounds__(256) void k_final9(const float* __restrict__ ws,
                                                float* __restrict__ out) {
  const int t = threadIdx.x;
  float loss = 0.f;
  for (int n = 0; n < NB; ++n) {
    float s = 0.f;
    for (int k = 0; k < 16; ++k)
      s += __expf(ws[OFF_MAXV + n*HW + k*256 + t]);
    const float tot = blockSum256(s);
    loss += -logf(tot*(1.0f/4096.0f) + kEPS);
  }
  if (t == 0) out[0] = loss*0.25f;
}

extern "C" void kernel_launch(void* const* d_in, const int* in_sizes, int n_in,
                              void* d_out, int out_size, void* d_ws, size_t ws_size,
                              hipStream_t stream) {
  const float* fT = (const float*)d_in[0];
  const float* fI = (const float*)d_in[1];
  float* out = (float*)d_out;
  float* ws  = (float*)d_ws;

  const size_t need_full = (size_t)WS_FLOATS_FULL * sizeof(float);
  if (ws_size < need_full) return;  // ~19 MB

  const ushort* GT = (const ushort*)(ws + OFF_GT);
  const ushort* GI = (const ushort*)(ws + OFF_GI);
  k_mean9 <<<256,  256, 0, stream>>>(fT, ws);
  k_prep9 <<<1024, 256, 0, stream>>>(fT, fI, ws);
  k_gA    <<<512,  256, 0, stream>>>(GT, GI, ws);   // colmax partials
  k_gB    <<<512,  256, 0, stream>>>(GT, GI, ws);   // Wsum partials
  k_gC    <<<512,  256, 0, stream>>>(GT, GI, ws);   // maxv strip partials
  k_red   <<<64,   256, 0, stream>>>(ws);           // strip combine
  k_final9<<<1,    256, 0, stream>>>(ws, out);
}

// Round 9
// 173.254 us; speedup vs baseline: 1.5550x; 1.1593x over previous
//
#include <hip/hip_runtime.h>
#include <cmath>

// CXLoss pipeline, revision 27.
// R26 post-mortem: gC's 5-level shfl tree = 160 ds_bpermute/thread/iter (~25us
// of LDS pipe) -- shfl is LDS, not VALU. K_A=2 doesn't change reads/MFMA
// (=1/K_B always) -> reverted gA/gB to R24 (their best measured structure).
// gC fix: OPERAND SWAP. The R14 fragment tiling is symmetric (lane&31 = A-row
// = B-col, same k map), so mfma(breg, afrag) yields the transposed tile:
// col=lane&31 -> p, reg -> q. Max over q = 31 in-register fmax (VALU, idle
// pipe) + one shfl_xor(32). gamma/beta per q-row via LDS broadcast table
// (exact k_gb9 formula/order). Per-wave maxima stashed in LDS; MAXP stored
// once at the end. Same dot products, same kc order -> S bit-identical.

#define NB 4
#define CC 256
#define HW 4096
#define NQ0 8    // p-slab loop-split (CMAX/WSUM partials)
#define NCS 16   // q col-strips (MAXP partials)

static constexpr float kEPS = 1e-8f;
static constexpr float kSIG = 0.1f + 1e-8f;

typedef __attribute__((ext_vector_type(8)))  short short8;
typedef __attribute__((ext_vector_type(16))) float f32x16;

// workspace layout (float units)
enum {
  OFF_MEAN = 0,                        // 256 channel means
  OFF_CMAX = 256,                      // NQ0*NB*HW colmax partials
  OFF_WSUM = OFF_CMAX + NQ0*NB*HW,     // NQ0*NB*HW Wsum partials
  OFF_MAXP = OFF_WSUM + NQ0*NB*HW,     // NCS*NB*HW maxv partials (1MB)
  OFF_MAXV = OFF_MAXP + NCS*NB*HW,     // NB*HW maxv
  OFF_GT   = OFF_MAXV + NB*HW,         // NB*HW*CC bf16, fragment-tiled
  OFF_GI   = OFF_GT + NB*HW*CC/2,
  WS_FLOATS_FULL = OFF_GI + NB*HW*CC/2
};

__device__ __forceinline__ ushort cvt_bf16(float x) {
  unsigned u = __float_as_uint(x);
  unsigned r = (u + 0x7fffu + ((u >> 16) & 1u)) >> 16;  // round-nearest-even
  return (ushort)r;
}

__device__ __forceinline__ void glds16(const ushort* g, ushort* l) {
  __builtin_amdgcn_global_load_lds(
      (const __attribute__((address_space(1))) unsigned*)g,
      (__attribute__((address_space(3))) unsigned*)l, 16, 0, 0);
}
__device__ __forceinline__ void s_bar()  { asm volatile("s_barrier" ::: "memory"); }
__device__ __forceinline__ void w_vm4()  { asm volatile("s_waitcnt vmcnt(4)" ::: "memory"); }
__device__ __forceinline__ void w_vm0()  { asm volatile("s_waitcnt vmcnt(0)" ::: "memory"); }
__device__ __forceinline__ void w_lgkm() { asm volatile("s_waitcnt lgkmcnt(0)" ::: "memory"); }

__device__ __forceinline__ float blockSum256(float v) {
  __shared__ float sh[4];
  const int lane = threadIdx.x & 63, wv = threadIdx.x >> 6;
  #pragma unroll
  for (int o = 32; o > 0; o >>= 1) v += __shfl_down(v, o, 64);
  __syncthreads();
  if (lane == 0) sh[wv] = v;
  __syncthreads();
  return sh[0] + sh[1] + sh[2] + sh[3];
}

// K1: per-channel mean of featureT. grid=256
__global__ __launch_bounds__(256) void k_mean9(const float* __restrict__ fT,
                                               float* __restrict__ ws) {
  const int c = blockIdx.x, t = threadIdx.x;
  float s = 0.f;
  for (int n = 0; n < NB; ++n) {
    const float* p = fT + (size_t)(n*CC + c)*HW;
    #pragma unroll
    for (int k = 0; k < 16; ++k) s += p[k*256 + t];
  }
  const float tot = blockSum256(s);
  if (t == 0) ws[OFF_MEAN + c] = tot * (1.0f/16384.0f);
}

// K2: fused normalize + fragment-tiled bf16 write (verified R14 layout):
// offset_ushort(n, r32, kc) = ((n*128 + r32)*16 + kc)*512 + l*8
//   holds X[n][p = r32*32 + (l&31)][c = kc*16 + (l>>5)*8 + j], j<8.
// grid = 2 * NB * 128 = 1024 blocks.
__global__ __launch_bounds__(256) void k_prep9(const float* __restrict__ fT,
                                               const float* __restrict__ fI,
                                               float* __restrict__ ws) {
  __shared__ float stage[32][257];
  __shared__ float prt[8][32];
  __shared__ float sinv[32];
  const int t = threadIdx.x, l = t & 63;
  int bid = blockIdx.x;
  const int tensor = (bid >= 512); bid &= 511;
  const int n   = bid >> 7;
  const int r32 = bid & 127;
  const int p0  = r32 * 32;

  const float* __restrict__ src = tensor ? fI : fT;
  ushort* __restrict__ dst = (ushort*)(ws + (tensor ? OFF_GI : OFF_GT));
  const float* __restrict__ mean = ws + OFF_MEAN;

  const int pl = t & 31, cg = t >> 5;
  float acc = 0.f;
  #pragma unroll
  for (int i = 0; i < 32; ++i) {
    const int c = cg*32 + i;
    const float v = src[((size_t)(n*CC + c))*HW + p0 + pl] - mean[c];
    stage[pl][c] = v;
    acc += v*v;
  }
  prt[cg][pl] = acc;
  __syncthreads();
  if (t < 32) {
    float s = 0.f;
    #pragma unroll
    for (int g = 0; g < 8; ++g) s += prt[g][t];
    sinv[t] = 1.0f/(sqrtf(s) + kEPS);
  }
  __syncthreads();

  const int w = t >> 6, lhi = l >> 5, m = l & 31;
  const float iv = sinv[m];
  #pragma unroll
  for (int i = 0; i < 4; ++i) {
    const int kc = w*4 + i;
    const int cb = kc*16 + lhi*8;
    short8 o;
    #pragma unroll
    for (int j = 0; j < 8; ++j)
      ((ushort*)&o)[j] = cvt_bf16(stage[m][cb + j] * iv);
    *(short8*)(dst + (((size_t)(n*128 + r32)*16 + kc) << 9) + l*8) = o;
  }
}

// ---- shared sweep geometry (K_B=2, glds + counted vmcnt, R24 structure) ----
// L: xcd = L&7, g = L>>3; nh = xcd*4 + (g&3); cs = g>>2.
// n = nh>>3, h = nh&7, col0 = cs*256.
// wave w: B col-tiles RB0 = cs*8+w, RB1 = cs*8+4+w; lane q0 = col0+w*32+ln31,
// q1 = q0+128. Per iter: glds tile -> Ab[iter&1]; 16 kc: 1 ds_read -> 2 MFMA.
// C/D map: col = lane&31, row = (r&3) + 8*(r>>2) + 4*(lane>>5).

// K3a: GEMM sweep + colmax partials. grid 512.
__global__ __launch_bounds__(256, 2) void k_gA(
    const ushort* __restrict__ gA, const ushort* __restrict__ gB,
    float* __restrict__ ws)
{
  __shared__ ushort Ab[2][8192];
  __shared__ float red2[256];

  const int t = threadIdx.x;
  const int w = t >> 6, l = t & 63;
  const int ln31 = l & 31;

  const int L = blockIdx.x;
  const int xcd = L & 7, g = L >> 3;
  const int nh = xcd*4 + (g & 3);
  const int cs = g >> 2;
  const int n = nh >> 3, h = nh & 7;
  const int col0 = cs * 256;

  const ushort* __restrict__ gAn = gA + ((size_t)(n*128 + h*16) << 13);

  // prologue: async-stage tiles 0,1
  #pragma unroll
  for (int i = 0; i < 4; ++i)
    glds16(gAn + (size_t)(i*256 + t)*8, &Ab[0][(i*256 + t)*8]);
  #pragma unroll
  for (int i = 0; i < 4; ++i)
    glds16(gAn + 8192 + (size_t)(i*256 + t)*8, &Ab[1][(i*256 + t)*8]);

  short8 breg0[16], breg1[16];
  {
    const int RB0 = cs*8 + w, RB1 = cs*8 + 4 + w;
    #pragma unroll
    for (int kc = 0; kc < 16; ++kc) {
      breg0[kc] = *(const short8*)(gB + (((size_t)(n*128 + RB0)*16 + kc) << 9) + l*8);
      breg1[kc] = *(const short8*)(gB + (((size_t)(n*128 + RB1)*16 + kc) << 9) + l*8);
    }
  }

  float run0 = -3.0e38f, run1 = -3.0e38f;

  for (int iter = 0; iter < 16; ++iter) {
    if (iter < 15) w_vm4(); else w_vm0();
    s_bar();                                   // Ab[iter&1] staged (all waves)

    const ushort* __restrict__ Abuf = &Ab[iter & 1][0];
    f32x16 acc0, acc1;
    #pragma unroll
    for (int e = 0; e < 16; ++e) { acc0[e] = 0.f; acc1[e] = 0.f; }
    #pragma unroll
    for (int kc = 0; kc < 16; ++kc) {
      const short8 a0 = *(const short8*)&Abuf[kc*512 + l*8];
      acc0 = __builtin_amdgcn_mfma_f32_32x32x16_bf16(a0, breg0[kc], acc0, 0, 0, 0);
      acc1 = __builtin_amdgcn_mfma_f32_32x32x16_bf16(a0, breg1[kc], acc1, 0, 0, 0);
    }
    w_lgkm();
    s_bar();                                   // all waves done reading Ab[iter&1]
    if (iter + 2 < 16) {
      const ushort* __restrict__ src = gAn + (size_t)(iter + 2)*8192;
      ushort* __restrict__ dstl = &Ab[iter & 1][0];
      #pragma unroll
      for (int i = 0; i < 4; ++i)
        glds16(src + (size_t)(i*256 + t)*8, dstl + (i*256 + t)*8);
    }

    #pragma unroll
    for (int r = 0; r < 16; ++r) {
      run0 = fmaxf(run0, acc0[r]);
      run1 = fmaxf(run1, acc1[r]);
    }
  }

  run0 = fmaxf(run0, __shfl_xor(run0, 32, 64));
  run1 = fmaxf(run1, __shfl_xor(run1, 32, 64));
  if (l < 32) {
    red2[w*32 + ln31]       = run0;
    red2[128 + w*32 + ln31] = run1;
  }
  __syncthreads();
  ws[OFF_CMAX + h*(NB*HW) + n*HW + col0 + t] = red2[t];
}

// K3b: GEMM sweep + Wsum partials. Per-lane a,b derived from CMAX.
__global__ __launch_bounds__(256, 2) void k_gB(
    const ushort* __restrict__ gA, const ushort* __restrict__ gB,
    float* __restrict__ ws)
{
  __shared__ ushort Ab[2][8192];
  __shared__ float red2[256];

  const int t = threadIdx.x;
  const int w = t >> 6, l = t & 63;
  const int ln31 = l & 31;

  const int L = blockIdx.x;
  const int xcd = L & 7, g = L >> 3;
  const int nh = xcd*4 + (g & 3);
  const int cs = g >> 2;
  const int n = nh >> 3, h = nh & 7;
  const int col0 = cs * 256;

  const ushort* __restrict__ gAn = gA + ((size_t)(n*128 + h*16) << 13);

  #pragma unroll
  for (int i = 0; i < 4; ++i)
    glds16(gAn + (size_t)(i*256 + t)*8, &Ab[0][(i*256 + t)*8]);
  #pragma unroll
  for (int i = 0; i < 4; ++i)
    glds16(gAn + 8192 + (size_t)(i*256 + t)*8, &Ab[1][(i*256 + t)*8]);

  // per-lane affine coeffs for both q columns (same op order as R24)
  float aq0, bq0, aq1, bq1;
  {
    const int q0 = col0 + w*32 + ln31;
    const int q1 = q0 + 128;
    float cm0 = -3.0e38f, cm1 = -3.0e38f;
    #pragma unroll
    for (int hh = 0; hh < NQ0; ++hh) {
      cm0 = fmaxf(cm0, ws[OFF_CMAX + hh*(NB*HW) + n*HW + q0]);
      cm1 = fmaxf(cm1, ws[OFF_CMAX + hh*(NB*HW) + n*HW + q1]);
    }
    const float i0 = 1.0f/(2.0f*(0.5f*(1.0f - cm0) + kEPS));
    const float i1 = 1.0f/(2.0f*(0.5f*(1.0f - cm1) + kEPS));
    bq0 = i0 / kSIG; aq0 = (1.0f - i0) / kSIG;
    bq1 = i1 / kSIG; aq1 = (1.0f - i1) / kSIG;
  }

  short8 breg0[16], breg1[16];
  {
    const int RB0 = cs*8 + w, RB1 = cs*8 + 4 + w;
    #pragma unroll
    for (int kc = 0; kc < 16; ++kc) {
      breg0[kc] = *(const short8*)(gB + (((size_t)(n*128 + RB0)*16 + kc) << 9) + l*8);
      breg1[kc] = *(const short8*)(gB + (((size_t)(n*128 + RB1)*16 + kc) << 9) + l*8);
    }
  }

  float ws0 = 0.f, ws1 = 0.f;

  for (int iter = 0; iter < 16; ++iter) {
    if (iter < 15) w_vm4(); else w_vm0();
    s_bar();

    const ushort* __restrict__ Abuf = &Ab[iter & 1][0];
    f32x16 acc0, acc1;
    #pragma unroll
    for (int e = 0; e < 16; ++e) { acc0[e] = 0.f; acc1[e] = 0.f; }
    #pragma unroll
    for (int kc = 0; kc < 16; ++kc) {
      const short8 a0 = *(const short8*)&Abuf[kc*512 + l*8];
      acc0 = __builtin_amdgcn_mfma_f32_32x32x16_bf16(a0, breg0[kc], acc0, 0, 0, 0);
      acc1 = __builtin_amdgcn_mfma_f32_32x32x16_bf16(a0, breg1[kc], acc1, 0, 0, 0);
    }
    w_lgkm();
    s_bar();
    if (iter + 2 < 16) {
      const ushort* __restrict__ src = gAn + (size_t)(iter + 2)*8192;
      ushort* __restrict__ dstl = &Ab[iter & 1][0];
      #pragma unroll
      for (int i = 0; i < 4; ++i)
        glds16(src + (size_t)(i*256 + t)*8, dstl + (i*256 + t)*8);
    }

    #pragma unroll
    for (int r = 0; r < 16; ++r) {
      ws0 += __expf(fmaf(bq0, acc0[r], aq0));
      ws1 += __expf(fmaf(bq1, acc1[r], aq1));
    }
  }

  ws0 += __shfl_xor(ws0, 32, 64);
  ws1 += __shfl_xor(ws1, 32, 64);
  if (l < 32) {
    red2[w*32 + ln31]       = ws0;
    red2[128 + w*32 + ln31] = ws1;
  }
  __syncthreads();
  ws[OFF_WSUM + h*(NB*HW) + n*HW + col0 + t] = red2[t];
}

// K3c: GEMM sweep + row-max (maxv) partials, SWAPPED operands:
// acc = mfma(breg, afrag) -> col(lane&31) = p, reg = q. Max over q is an
// in-register fmax chain + one shfl_xor(32). gamma/beta per q-row from a
// per-block LDS table (exact k_gb9 formula/order). Per-wave maxima stashed
// in LDS; MAXP written once at the end.
__global__ __launch_bounds__(256, 2) void k_gC(
    const ushort* __restrict__ gA, const ushort* __restrict__ gB,
    float* __restrict__ ws)
{
  __shared__ ushort Ab[2][8192];
  __shared__ float gam_s[256], bet_s[256];
  __shared__ float stash[4][512];   // 8KB: per-wave p-maxima

  const int t = threadIdx.x;
  const int w = t >> 6, l = t & 63;
  const int ln31 = l & 31, lhi = l >> 5;

  const int L = blockIdx.x;
  const int xcd = L & 7, g = L >> 3;
  const int nh = xcd*4 + (g & 3);
  const int cs = g >> 2;
  const int n = nh >> 3, h = nh & 7;
  const int col0 = cs * 256;

  const ushort* __restrict__ gAn = gA + ((size_t)(n*128 + h*16) << 13);

  #pragma unroll
  for (int i = 0; i < 4; ++i)
    glds16(gAn + (size_t)(i*256 + t)*8, &Ab[0][(i*256 + t)*8]);
  #pragma unroll
  for (int i = 0; i < 4; ++i)
    glds16(gAn + 8192 + (size_t)(i*256 + t)*8, &Ab[1][(i*256 + t)*8]);

  // gamma/beta table for this block's 256 q (formula/order == old k_gb9)
  {
    const int idx = n*HW + col0 + t;
    float cm = -3.0e38f;
    #pragma unroll
    for (int hh = 0; hh < NQ0; ++hh)
      cm = fmaxf(cm, ws[OFF_CMAX + hh*(NB*HW) + idx]);
    float sw = 0.f;
    #pragma unroll
    for (int hh = 0; hh < NQ0; ++hh)
      sw += ws[OFF_WSUM + hh*(NB*HW) + idx];
    const float i0 = 1.0f/(2.0f*(0.5f*(1.0f - cm) + kEPS));
    bet_s[t] = i0 / kSIG;
    gam_s[t] = (1.0f - i0) / kSIG - logf(sw + kEPS);
  }

  short8 breg0[16], breg1[16];
  {
    const int RB0 = cs*8 + w, RB1 = cs*8 + 4 + w;
    #pragma unroll
    for (int kc = 0; kc < 16; ++kc) {
      breg0[kc] = *(const short8*)(gB + (((size_t)(n*128 + RB0)*16 + kc) << 9) + l*8);
      breg1[kc] = *(const short8*)(gB + (((size_t)(n*128 + RB1)*16 + kc) << 9) + l*8);
    }
  }
  __syncthreads();   // gam/bet table ready (also covers stash init ordering)

  for (int iter = 0; iter < 16; ++iter) {
    if (iter < 15) w_vm4(); else w_vm0();
    s_bar();                                   // Ab[iter&1] staged

    const ushort* __restrict__ Abuf = &Ab[iter & 1][0];
    f32x16 accq0, accq1;                       // rows = q, cols = p (swapped)
    #pragma unroll
    for (int e = 0; e < 16; ++e) { accq0[e] = 0.f; accq1[e] = 0.f; }
    #pragma unroll
    for (int kc = 0; kc < 16; ++kc) {
      const short8 a0 = *(const short8*)&Abuf[kc*512 + l*8];
      accq0 = __builtin_amdgcn_mfma_f32_32x32x16_bf16(breg0[kc], a0, accq0, 0, 0, 0);
      accq1 = __builtin_amdgcn_mfma_f32_32x32x16_bf16(breg1[kc], a0, accq1, 0, 0, 0);
    }
    w_lgkm();
    s_bar();
    if (iter + 2 < 16) {
      const ushort* __restrict__ src = gAn + (size_t)(iter + 2)*8192;
      ushort* __restrict__ dstl = &Ab[iter & 1][0];
      #pragma unroll
      for (int i = 0; i < 4; ++i)
        glds16(src + (size_t)(i*256 + t)*8, dstl + (i*256 + t)*8);
    }

    // epilogue: lane holds p = iter*32 + ln31; 16 q-rows per acc tile.
    float m = -3.0e38f;
    #pragma unroll
    for (int r = 0; r < 16; ++r) {
      const int row = (r & 3) + 8*(r >> 2) + 4*lhi;
      const float g0v = gam_s[w*32 + row],       b0v = bet_s[w*32 + row];
      const float g1v = gam_s[128 + w*32 + row], b1v = bet_s[128 + w*32 + row];
      m = fmaxf(m, fmaf(b0v, accq0[r], g0v));
      m = fmaxf(m, fmaf(b1v, accq1[r], g1v));
    }
    m = fmaxf(m, __shfl_xor(m, 32, 64));       // merge lhi q-halves
    if (l < 32) stash[w][iter*32 + ln31] = m;  // p-local = iter*32 + ln31
  }

  __syncthreads();
  float* __restrict__ MAXP = ws + OFF_MAXP + (size_t)cs*(NB*HW) + n*HW + h*512;
  #pragma unroll
  for (int p = t; p < 512; p += 256) {
    MAXP[p] = fmaxf(fmaxf(stash[0][p], stash[1][p]),
                    fmaxf(stash[2][p], stash[3][p]));
  }
}

// K6: combine 16 col-strip maxima. grid = 64.
__global__ __launch_bounds__(256) void k_red(float* __restrict__ ws) {
  const int idx = blockIdx.x*256 + threadIdx.x;   // n*HW + p
  float m = ws[OFF_MAXP + idx];
  #pragma unroll
  for (int s = 1; s < NCS; ++s)
    m = fmaxf(m, ws[OFF_MAXP + s*(NB*HW) + idx]);
  ws[OFF_MAXV + idx] = m;
}

// K7: final loss. one block.
__global__ __launch_bounds__(256) void k_final9(const float* __restrict__ ws,
                                                float* __restrict__ out) {
  const int t = threadIdx.x;
  float loss = 0.f;
  for (int n = 0; n < NB; ++n) {
    float s = 0.f;
    for (int k = 0; k < 16; ++k)
      s += __expf(ws[OFF_MAXV + n*HW + k*256 + t]);
    const float tot = blockSum256(s);
    loss += -logf(tot*(1.0f/4096.0f) + kEPS);
  }
  if (t == 0) out[0] = loss*0.25f;
}

extern "C" void kernel_launch(void* const* d_in, const int* in_sizes, int n_in,
                              void* d_out, int out_size, void* d_ws, size_t ws_size,
                              hipStream_t stream) {
  const float* fT = (const float*)d_in[0];
  const float* fI = (const float*)d_in[1];
  float* out = (float*)d_out;
  float* ws  = (float*)d_ws;

  const size_t need_full = (size_t)WS_FLOATS_FULL * sizeof(float);
  if (ws_size < need_full) return;  // ~19 MB

  const ushort* GT = (const ushort*)(ws + OFF_GT);
  const ushort* GI = (const ushort*)(ws + OFF_GI);
  k_mean9 <<<256,  256, 0, stream>>>(fT, ws);
  k_prep9 <<<1024, 256, 0, stream>>>(fT, fI, ws);
  k_gA    <<<512,  256, 0, stream>>>(GT, GI, ws);   // colmax partials
  k_gB    <<<512,  256, 0, stream>>>(GT, GI, ws);   // Wsum partials
  k_gC    <<<512,  256, 0, stream>>>(GT, GI, ws);   // maxv strip partials
  k_red   <<<64,   256, 0, stream>>>(ws);           // strip combine
  k_final9<<<1,    256, 0, stream>>>(ws, out);
}